// Round 4
// baseline (9036.091 us; speedup 1.0000x reference)
//
#include <hip/hip_runtime.h>
#include <hip/hip_bf16.h>
#include <math.h>

using f32x4 = __attribute__((ext_vector_type(4))) float;
using s16x8 = __attribute__((ext_vector_type(8))) short;
typedef unsigned short u16;

#define MFMA16(a,b,c) __builtin_amdgcn_mfma_f32_16x16x32_bf16(a,b,c,0,0,0)
#define SCOPE_A __HIP_MEMORY_SCOPE_AGENT

__device__ __forceinline__ float bf2f(u16 u){
  union { unsigned int i; float f; } v; v.i = ((unsigned int)u) << 16; return v.f;
}
__device__ __forceinline__ u16 f2bf(float f){
  union { float f; unsigned int i; } v; v.f = f;
  unsigned int x = v.i;
  return (u16)((x + 0x7fffu + ((x >> 16) & 1u)) >> 16);
}
__device__ __forceinline__ float sigm(float x){ return 1.0f/(1.0f + expf(-x)); }

__device__ __forceinline__ s16x8 pack8(const float* p){
  s16x8 r;
  #pragma unroll
  for (int i = 0; i < 8; ++i) r[i] = (short)f2bf(p[i]);
  return r;
}

// flag-based grid barrier: no atomic contention. flags[nb], rel zeroed pre-launch.
__device__ __forceinline__ void gbarf(int* flags, int* rel, int nb, int gen){
  __syncthreads();
  if (threadIdx.x == 0){
    __threadfence();
    __hip_atomic_store(flags + blockIdx.x, gen, __ATOMIC_RELEASE, SCOPE_A);
  }
  if (blockIdx.x == 0){
    for (int i = threadIdx.x; i < nb; i += blockDim.x)
      while (__hip_atomic_load(flags + i, __ATOMIC_ACQUIRE, SCOPE_A) < gen)
        __builtin_amdgcn_s_sleep(1);
    __syncthreads();
    if (threadIdx.x == 0)
      __hip_atomic_store(rel, gen, __ATOMIC_RELEASE, SCOPE_A);
  }
  if (threadIdx.x == 0){
    while (__hip_atomic_load(rel, __ATOMIC_ACQUIRE, SCOPE_A) < gen)
      __builtin_amdgcn_s_sleep(1);
    __threadfence();
  }
  __syncthreads();
}

// ---------------- small utility kernels ----------------
__global__ void k_zero(float* __restrict__ p, long n){
  long i = (long)blockIdx.x*blockDim.x + threadIdx.x;
  long st = (long)gridDim.x*blockDim.x;
  for (; i < n; i += st) p[i] = 0.0f;
}

__global__ void k_cast_bf16(const float* __restrict__ src, u16* __restrict__ dst, long n){
  long i = ((long)blockIdx.x*blockDim.x + threadIdx.x)*4;
  long st = (long)gridDim.x*blockDim.x*4;
  for (; i < n; i += st){
    float4 v = *(const float4*)(src + i);
    *(ushort4*)(dst + i) = make_ushort4(f2bf(v.x), f2bf(v.y), f2bf(v.z), f2bf(v.w));
  }
}

__global__ void k_addv(const float* __restrict__ a, const float* __restrict__ b,
                       float* __restrict__ d, int n){
  int i = blockIdx.x*blockDim.x + threadIdx.x;
  if (i < n) d[i] = a[i] + b[i];
}

// cnn_w (512,512,2) -> Wconv_bf [512][1024] = [W0 | W1]
__global__ void k_repack_conv(const float* __restrict__ w, u16* __restrict__ dst){
  int i = blockIdx.x*256 + threadIdx.x;
  int o = i >> 9, ii = i & 511;
  dst[(size_t)o*1024 + ii]       = f2bf(w[((size_t)o*512 + ii)*2 + 0]);
  dst[(size_t)o*1024 + 512 + ii] = f2bf(w[((size_t)o*512 + ii)*2 + 1]);
}

// Wy[4096][512] = dec_Wih[:, 1024:1536]
__global__ void k_build_wy(const float* __restrict__ dWih, u16* __restrict__ Wy){
  int i = blockIdx.x*256 + threadIdx.x; // 4096*512
  int r = i >> 9, c = i & 511;
  Wy[(size_t)r*512 + c] = f2bf(dWih[(size_t)r*1536 + 1024 + c]);
}

// Wcomb (1024,3072) -> Wca [1024][2048], Whp [1024][1024]
__global__ void k_split_wcomb(const float* __restrict__ Wcomb,
                              u16* __restrict__ Wca, u16* __restrict__ Whp){
  int r = blockIdx.x; // 1024
  for (int c = threadIdx.x; c < 2048; c += 256)
    Wca[(size_t)r*2048 + c] = f2bf(Wcomb[(size_t)r*3072 + c]);
  for (int c = threadIdx.x; c < 1024; c += 256)
    Whp[(size_t)r*1024 + c] = f2bf(Wcomb[(size_t)r*3072 + 2048 + c]);
}

__global__ void k_gather_src(const int* __restrict__ ids, const float* __restrict__ emb,
                             u16* __restrict__ Aconv){
  int s = blockIdx.x;
  int b = blockIdx.y;
  int e = threadIdx.x*4;
  float4 v = make_float4(0.f,0.f,0.f,0.f);
  if (s < 48){ int id = ids[s*64 + b]; v = *(const float4*)(emb + (size_t)id*512 + e); }
  ushort4 u = make_ushort4(f2bf(v.x), f2bf(v.y), f2bf(v.z), f2bf(v.w));
  if (s < 48) *(ushort4*)(Aconv + ((size_t)(s*64 + b))*1024 + e) = u;
  if (s >= 1) *(ushort4*)(Aconv + ((size_t)((s-1)*64 + b))*1024 + 512 + e) = u;
}

__global__ void k_gather_y(const int* __restrict__ ids, const float* __restrict__ emb,
                           u16* __restrict__ Y){
  int t = blockIdx.x; int b = blockIdx.y; int e = threadIdx.x*4;
  int id = ids[t*64 + b];
  float4 v = *(const float4*)(emb + (size_t)id*512 + e);
  *(ushort4*)(Y + ((size_t)(t*64 + b))*512 + e) = make_ushort4(f2bf(v.x), f2bf(v.y), f2bf(v.z), f2bf(v.w));
}

// ---------------- universal MFMA GEMM (prologue use) ----------------
template<bool OUT_BF16>
__global__ __launch_bounds__(256) void k_gemm(
    const u16* __restrict__ A0, long lda0,
    const u16* __restrict__ A1, long lda1, int ksplit,
    const u16* __restrict__ W, int K,
    void* __restrict__ Out, long ldc,
    const float* __restrict__ bias)
{
  __shared__ __align__(16) u16 As[64][72];
  __shared__ __align__(16) u16 Ws[64][72];
  const int t = threadIdx.x;
  const int m0 = blockIdx.x*64, n0 = blockIdx.y*64;
  const int w = t >> 6, l = t & 63, lr = l & 15, lh = l >> 4;
  const int sr = t >> 2, sk = (t & 3) << 4;

  f32x4 acc[4] = {{0,0,0,0},{0,0,0,0},{0,0,0,0},{0,0,0,0}};

  for (int kc = 0; kc < K; kc += 64){
    {
      const u16* wp = W + (size_t)(n0 + sr)*K + kc + sk;
      *(s16x8*)&Ws[sr][sk]     = *(const s16x8*)wp;
      *(s16x8*)&Ws[sr][sk + 8] = *(const s16x8*)(wp + 8);
    }
    {
      const u16* ap = (kc < ksplit)
        ? A0 + (size_t)(m0 + sr)*lda0 + kc
        : A1 + (size_t)(m0 + sr)*lda1 + (kc - ksplit);
      ap += sk;
      *(s16x8*)&As[sr][sk]     = *(const s16x8*)ap;
      *(s16x8*)&As[sr][sk + 8] = *(const s16x8*)(ap + 8);
    }
    __syncthreads();
    #pragma unroll
    for (int kk = 0; kk < 64; kk += 32){
      s16x8 a = *(const s16x8*)&As[w*16 + lr][kk + lh*8];
      #pragma unroll
      for (int ct = 0; ct < 4; ++ct){
        s16x8 bfr = *(const s16x8*)&Ws[ct*16 + lr][kk + lh*8];
        acc[ct] = MFMA16(a, bfr, acc[ct]);
      }
    }
    __syncthreads();
  }
  #pragma unroll
  for (int ct = 0; ct < 4; ++ct){
    #pragma unroll
    for (int rr = 0; rr < 4; ++rr){
      long row = m0 + w*16 + lh*4 + rr;
      long col = n0 + ct*16 + lr;
      float v = acc[ct][rr];
      if (bias) v += bias[col];
      long oi = row*ldc + col;
      if (OUT_BF16) ((u16*)Out)[oi] = f2bf(v);
      else          ((float*)Out)[oi] = v;
    }
  }
}

// ---------------- persistent encoder ----------------
// 256 blocks: dir = blk>>7, 8 hidden units x 4 gates per block (32 W-rows in LDS).
// W slice LDS-resident (64KB, swizzled). A read direct global->frag. 1 barrier/step.
__global__ __launch_bounds__(256) void k_enc_persist(
    const float* __restrict__ WhhF, const float* __restrict__ WhhB,
    const u16* __restrict__ Gf, const u16* __restrict__ Gb,
    u16* __restrict__ hF0, u16* __restrict__ hF1,
    u16* __restrict__ hB0, u16* __restrict__ hB1,
    float* __restrict__ cF, float* __restrict__ cB,
    u16* __restrict__ Aatt, u16* __restrict__ cfbf, u16* __restrict__ cbbf,
    int* flags, int* rel)
{
  extern __shared__ char smem[];   // W slice [32][1024] bf16 swizzled, ROWB=2048
  const int t = threadIdx.x, blk = blockIdx.x;
  const int dir = blk >> 7;
  const int j0 = (blk & 127) << 3;
  const float* Wsrc = dir ? WhhB : WhhF;
  const u16* G = dir ? Gb : Gf;
  float* c = dir ? cB : cF;
  u16* cobf = dir ? cbbf : cfbf;
  u16* h0 = dir ? hB0 : hF0;
  u16* h1 = dir ? hB1 : hF1;

  // stage W slice (rows ordered [g*8 + jj]) with XOR swizzle
  for (int q = t; q < 32*128; q += 256){
    int row = q >> 7;
    int ck = (q & 127) << 3;
    int wrow = ((row >> 3)*1024) + j0 + (row & 7);
    s16x8 pk = pack8(Wsrc + (size_t)wrow*1024 + ck);
    *(s16x8*)(smem + row*2048 + ((ck*2) ^ ((row & 7) << 4))) = pk;
  }
  __syncthreads();

  const int w = t >> 6, l = t & 63, lr = l & 15, lh = l >> 4;
  const int lane_m = w*16 + lr;
  const int koff = lh*8;
  const char* wp0 = smem + lr*2048;
  const char* wp1 = smem + (16 + lr)*2048;
  const int xo = (lr & 7) << 4;
  const int jj = lr & 7, gsel = lr >> 3;
  const int j = j0 + jj;
  int gen = 0;

  for (int s = 0; s < 48; ++s){
    const u16* hin = (s & 1) ? h1 : h0;
    u16* hout      = (s & 1) ? h0 : h1;
    const int time = dir ? 47 - s : s;
    f32x4 a0 = {0,0,0,0}, a1 = {0,0,0,0};
    const u16* ap = hin + (size_t)lane_m*1024 + koff;
    #pragma unroll 8
    for (int kc = 0; kc < 1024; kc += 32){
      s16x8 av = *(const s16x8*)(ap + kc);
      int cb = (kc + koff)*2;
      s16x8 b0 = *(const s16x8*)(wp0 + (cb ^ xo));
      s16x8 b1 = *(const s16x8*)(wp1 + (cb ^ xo));
      a0 = MFMA16(av, b0, a0);
      a1 = MFMA16(av, b1, a1);
    }
    #pragma unroll
    for (int rr = 0; rr < 4; ++rr){
      float v0 = a0[rr], v1 = a1[rr];
      float p0 = __shfl_xor(v0, 8, 64);
      float p1 = __shfl_xor(v1, 8, 64);
      if (gsel == 0){
        int b = w*16 + lh*4 + rr;
        size_t grow = ((size_t)time*64 + b)*4096;
        float gi = v0 + bf2f(G[grow + j]);
        float gf = p0 + bf2f(G[grow + 1024 + j]);
        float gg = v1 + bf2f(G[grow + 2048 + j]);
        float go = p1 + bf2f(G[grow + 3072 + j]);
        float cn = sigm(gf)*c[b*1024 + j] + sigm(gi)*tanhf(gg);
        float hn = sigm(go)*tanhf(cn);
        c[b*1024 + j] = cn;
        u16 hb = f2bf(hn);
        hout[b*1024 + j] = hb;
        Aatt[((size_t)b*48 + time)*2048 + dir*1024 + j] = hb;
        if (s == 47) cobf[b*1024 + j] = f2bf(cn);
      }
    }
    if (s < 47) gbarf(flags, rel, 256, ++gen);
  }
}

// ---------------- persistent decoder ----------------
// 256 blocks: 0..127 G-blocks (Wdec slice 128KB LDS), 128..255 AW-blocks
// (encP half + encWc half, 96KB LDS). 3 barriers/step.
__global__ __launch_bounds__(256) void k_dec_persist(
    const float* __restrict__ dWih, const float* __restrict__ dWhh,
    const u16* __restrict__ Gy,
    const u16* __restrict__ encP, const u16* __restrict__ encWc,
    const u16* __restrict__ Whp,
    u16* __restrict__ hbf0, u16* __restrict__ hbf1,
    float* __restrict__ cdec,
    float* __restrict__ hpart, float* __restrict__ sc,
    float* __restrict__ combined, u16* __restrict__ Cbf,
    const u16* __restrict__ obf_zero,
    int* flags, int* rel)
{
  extern __shared__ char smem[];
  const int t = threadIdx.x, blk = blockIdx.x;
  const int w = t >> 6, l = t & 63, lr = l & 15, lh = l >> 4;
  const int lane_m = w*16 + lr;
  const int koff = lh*8;

  // AW LDS carve
  u16* ePl = (u16*)smem;                  // [48][512]
  u16* eWl = (u16*)(smem + 49152);        // [48][512]
  float* hs = (float*)(smem + 98304);     // [512]
  float* es = (float*)(smem + 100352);    // [48]
  float* ea = es + 48;                    // [48]

  const int aidx = blk - 128;
  const int ab = aidx >> 1, kh = aidx & 1;

  if (blk < 128){
    // stage Wdec slice: 32 rows x 2048 (cols 0..1023 from dWih, 1024..2047 from dWhh)
    const int j0 = blk << 3;
    for (int q = t; q < 32*256; q += 256){
      int row = q >> 8;
      int ck = (q & 255) << 3;
      int wrow = ((row >> 3)*1024) + j0 + (row & 7);
      const float* src = (ck < 1024) ? dWih + (size_t)wrow*1536 + ck
                                     : dWhh + (size_t)wrow*1024 + (ck - 1024);
      s16x8 pk = pack8(src);
      *(s16x8*)(smem + row*4096 + ((ck*2) ^ ((row & 7) << 4))) = pk;
    }
  } else {
    // stage encP half + encWc half for batch row ab
    for (int q = t; q < 48*64; q += 256){
      int s = q >> 6;
      int ck = (q & 63) << 3;
      *(s16x8*)(ePl + s*512 + ck) =
        *(const s16x8*)(encP + ((size_t)ab*48 + s)*1024 + kh*512 + ck);
      *(s16x8*)(eWl + s*512 + ck) =
        *(const s16x8*)(encWc + ((size_t)ab*48 + s)*1024 + kh*512 + ck);
    }
  }
  __syncthreads();

  const int j0 = (blk & 127) << 3;
  const int jj = lr & 7, gsel = lr >> 3;
  const int j = j0 + jj;
  const char* wp0 = smem + lr*4096;
  const char* wp1 = smem + (16 + lr)*4096;
  const int xo = (lr & 7) << 4;

  int gen = 0;
  int cur = 0;

  for (int tt = 0; tt < 47; ++tt){
    const u16* hin  = cur ? hbf1 : hbf0;
    u16* hnew       = cur ? hbf0 : hbf1;

    if (blk < 128){
      // ---- ph1: gates = [o_prev | h] @ Wdec_slice^T + Gy -> LSTM
      const u16* Ao = tt ? (Cbf + (size_t)(tt - 1)*65536) : obf_zero;
      f32x4 a0 = {0,0,0,0}, a1 = {0,0,0,0};
      {
        const u16* ap = Ao + (size_t)lane_m*1024 + koff;
        #pragma unroll 8
        for (int kc = 0; kc < 1024; kc += 32){
          s16x8 av = *(const s16x8*)(ap + kc);
          int cb = (kc + koff)*2;
          s16x8 b0 = *(const s16x8*)(wp0 + (cb ^ xo));
          s16x8 b1 = *(const s16x8*)(wp1 + (cb ^ xo));
          a0 = MFMA16(av, b0, a0);
          a1 = MFMA16(av, b1, a1);
        }
      }
      {
        const u16* ap = hin + (size_t)lane_m*1024 + koff;
        #pragma unroll 8
        for (int kc = 0; kc < 1024; kc += 32){
          s16x8 av = *(const s16x8*)(ap + kc);
          int cb = (kc + 1024 + koff)*2;
          s16x8 b0 = *(const s16x8*)(wp0 + (cb ^ xo));
          s16x8 b1 = *(const s16x8*)(wp1 + (cb ^ xo));
          a0 = MFMA16(av, b0, a0);
          a1 = MFMA16(av, b1, a1);
        }
      }
      #pragma unroll
      for (int rr = 0; rr < 4; ++rr){
        float v0 = a0[rr], v1 = a1[rr];
        float p0 = __shfl_xor(v0, 8, 64);
        float p1 = __shfl_xor(v1, 8, 64);
        if (gsel == 0){
          int b = w*16 + lh*4 + rr;
          size_t grow = ((size_t)tt*64 + b)*4096;
          float gi = v0 + bf2f(Gy[grow + j]);
          float gf = p0 + bf2f(Gy[grow + 1024 + j]);
          float gg = v1 + bf2f(Gy[grow + 2048 + j]);
          float go = p1 + bf2f(Gy[grow + 3072 + j]);
          float cn = sigm(gf)*cdec[b*1024 + j] + sigm(gi)*tanhf(gg);
          float hn = sigm(go)*tanhf(cn);
          cdec[b*1024 + j] = cn;
          hnew[b*1024 + j] = f2bf(hn);
        }
      }
    }
    gbarf(flags, rel, 256, ++gen);

    if (blk >= 128){
      // ---- ph2 (AW): partial scores over kh half
      for (int i = t; i < 512; i += 256)
        hs[i] = bf2f(hnew[(size_t)ab*1024 + kh*512 + i]);
      __syncthreads();
      for (int s = w; s < 48; s += 4){
        float p = 0.f;
        #pragma unroll
        for (int i = 0; i < 8; ++i)
          p += hs[l + 64*i]*bf2f(ePl[s*512 + l + 64*i]);
        #pragma unroll
        for (int d = 32; d >= 1; d >>= 1) p += __shfl_xor(p, d, 64);
        if (l == 0) sc[(ab*2 + kh)*48 + s] = p;
      }
    } else if (blk < 64){
      // ---- ph2 (G 0..63): hpart = hnew @ Whp^T, 16 cols each
      const int n0 = blk << 4;
      const u16* ap = hnew + (size_t)lane_m*1024 + koff;
      const u16* wb = Whp + (size_t)(n0 + lr)*1024 + koff;
      f32x4 acc = {0,0,0,0};
      #pragma unroll 8
      for (int kc = 0; kc < 1024; kc += 32){
        s16x8 av = *(const s16x8*)(ap + kc);
        s16x8 bv = *(const s16x8*)(wb + kc);
        acc = MFMA16(av, bv, acc);
      }
      #pragma unroll
      for (int rr = 0; rr < 4; ++rr)
        hpart[(size_t)(w*16 + lh*4 + rr)*1024 + n0 + lr] = acc[rr];
    }
    gbarf(flags, rel, 256, ++gen);

    if (blk >= 128){
      // ---- ph3 (AW): softmax + weighted encWc sum + combine
      if (t < 48) es[t] = sc[ab*96 + t] + sc[ab*96 + 48 + t];
      __syncthreads();
      float m = -INFINITY;
      for (int s = 0; s < 48; ++s) m = fmaxf(m, es[s]);
      if (t < 48) ea[t] = expf(es[t] - m);
      __syncthreads();
      float ssum = 0.f;
      for (int s = 0; s < 48; ++s) ssum += ea[s];
      float inv = 1.0f/ssum;
      int c0 = t*2;
      float acc0 = 0.f, acc1 = 0.f;
      for (int s = 0; s < 48; ++s){
        float wgt = ea[s];
        acc0 += wgt*bf2f(eWl[s*512 + c0]);
        acc1 += wgt*bf2f(eWl[s*512 + c0 + 1]);
      }
      int n = kh*512 + c0;
      float v0 = tanhf(hpart[(size_t)ab*1024 + n]     + acc0*inv);
      float v1 = tanhf(hpart[(size_t)ab*1024 + n + 1] + acc1*inv);
      size_t oi = (size_t)tt*65536 + (size_t)ab*1024 + n;
      combined[oi]     = v0;
      combined[oi + 1] = v1;
      Cbf[oi]     = f2bf(v0);
      Cbf[oi + 1] = f2bf(v1);
      __syncthreads();
    }
    if (tt < 46) gbarf(flags, rel, 256, ++gen);
    cur ^= 1;
  }
}

// ---------------- fused vocab GEMM + online logsumexp ----------------
#define VNS 25
__global__ __launch_bounds__(256) void k_vocab_lse(
    const u16* __restrict__ Cbf, const u16* __restrict__ Wv, float2* __restrict__ partials)
{
  __shared__ __align__(16) u16 As[64][136];
  __shared__ __align__(16) u16 Ws[64][136];
  int rb = blockIdx.x, sp = blockIdx.y;
  int m0 = rb*64;
  int t = threadIdx.x, w = t >> 6, l = t & 63, lr = l & 15, lh = l >> 4;
  int sr = t >> 2, sk = (t & 3) << 5;
  float mrun[4] = {-INFINITY, -INFINITY, -INFINITY, -INFINITY};
  float srun[4] = {0.f, 0.f, 0.f, 0.f};

  for (int nt = 0; nt < 20; ++nt){
    int n0 = sp*1280 + nt*64;
    f32x4 acc[4] = {{0,0,0,0},{0,0,0,0},{0,0,0,0},{0,0,0,0}};
    for (int kc = 0; kc < 1024; kc += 128){
      const u16* ap = Cbf + (size_t)(m0 + sr)*1024 + kc + sk;
      const u16* wp = Wv  + (size_t)(n0 + sr)*1024 + kc + sk;
      #pragma unroll
      for (int q = 0; q < 4; ++q){
        *(s16x8*)&As[sr][sk + q*8] = *(const s16x8*)(ap + q*8);
        *(s16x8*)&Ws[sr][sk + q*8] = *(const s16x8*)(wp + q*8);
      }
      __syncthreads();
      #pragma unroll
      for (int kk = 0; kk < 128; kk += 32){
        s16x8 a = *(const s16x8*)&As[w*16 + lr][kk + lh*8];
        #pragma unroll
        for (int ct = 0; ct < 4; ++ct){
          s16x8 bfr = *(const s16x8*)&Ws[ct*16 + lr][kk + lh*8];
          acc[ct] = MFMA16(a, bfr, acc[ct]);
        }
      }
      __syncthreads();
    }
    #pragma unroll
    for (int rr = 0; rr < 4; ++rr){
      float tm = fmaxf(fmaxf(acc[0][rr], acc[1][rr]), fmaxf(acc[2][rr], acc[3][rr]));
      for (int d = 1; d < 16; d <<= 1) tm = fmaxf(tm, __shfl_xor(tm, d, 64));
      float ts = expf(acc[0][rr] - tm) + expf(acc[1][rr] - tm)
               + expf(acc[2][rr] - tm) + expf(acc[3][rr] - tm);
      for (int d = 1; d < 16; d <<= 1) ts += __shfl_xor(ts, d, 64);
      if (tm > mrun[rr]){ srun[rr] = srun[rr]*expf(mrun[rr] - tm) + ts; mrun[rr] = tm; }
      else srun[rr] += ts*expf(tm - mrun[rr]);
    }
  }
  if (lr == 0){
    #pragma unroll
    for (int rr = 0; rr < 4; ++rr){
      long row = m0 + w*16 + lh*4 + rr;
      partials[row*VNS + sp] = make_float2(mrun[rr], srun[rr]);
    }
  }
}

__global__ void k_lse(const float2* __restrict__ partials, float* __restrict__ lse){
  int r = blockIdx.x*256 + threadIdx.x;
  if (r >= 3008) return;
  float m = -INFINITY, s = 0.f;
  for (int i = 0; i < VNS; ++i){
    float2 p = partials[r*VNS + i];
    if (p.x > m){ s = s*expf(m - p.x) + p.y; m = p.x; }
    else s += p.y*expf(p.x - m);
  }
  lse[r] = m + logf(s);
}

__global__ __launch_bounds__(256) void k_gold(const float* __restrict__ combined,
                                              const float* __restrict__ Wv,
                                              const int* __restrict__ tgt,
                                              float* __restrict__ gold){
  int w = threadIdx.x >> 6, l = threadIdx.x & 63;
  int r = blockIdx.x*4 + w;
  int tt = r >> 6, b = r & 63;
  int gid = tgt[(tt + 1)*64 + b];
  const float* cp = combined + (size_t)r*1024;
  const float* wp = Wv + (size_t)gid*1024;
  float p = 0.f;
  for (int i = l; i < 1024; i += 64) p += cp[i]*wp[i];
  for (int d = 32; d >= 1; d >>= 1) p += __shfl_xor(p, d, 64);
  if (l == 0) gold[r] = p;
}

__global__ void k_final(const float* __restrict__ gold, const float* __restrict__ lse,
                        const int* __restrict__ tgt, float* __restrict__ out){
  int b = threadIdx.x;
  if (b >= 64) return;
  float acc = 0.f;
  for (int t = 0; t < 47; ++t){
    int gid = tgt[(t + 1)*64 + b];
    if (gid != 0) acc += gold[t*64 + b] - lse[t*64 + b];
  }
  out[b] = acc;
}

// ---------------- host ----------------
extern "C" void kernel_launch(void* const* d_in, const int* in_sizes, int n_in,
                              void* d_out, int out_size, void* d_ws, size_t ws_size,
                              hipStream_t stream)
{
  (void)in_sizes; (void)n_in; (void)out_size; (void)ws_size;
  const int*   src_ids = (const int*)d_in[0];
  const int*   tgt_ids = (const int*)d_in[1];
  const float* src_emb = (const float*)d_in[3];
  const float* tgt_emb = (const float*)d_in[4];
  const float* cnn_w   = (const float*)d_in[5];
  const float* cnn_b   = (const float*)d_in[6];
  const float* eWih_f  = (const float*)d_in[7];
  const float* eWhh_f  = (const float*)d_in[8];
  const float* ebih_f  = (const float*)d_in[9];
  const float* ebhh_f  = (const float*)d_in[10];
  const float* eWih_b  = (const float*)d_in[11];
  const float* eWhh_b  = (const float*)d_in[12];
  const float* ebih_b  = (const float*)d_in[13];
  const float* ebhh_b  = (const float*)d_in[14];
  const float* dWih    = (const float*)d_in[15];
  const float* dWhh    = (const float*)d_in[16];
  const float* dbih    = (const float*)d_in[17];
  const float* dbhh    = (const float*)d_in[18];
  const float* Wh      = (const float*)d_in[19];
  const float* Wc      = (const float*)d_in[20];
  const float* Watt    = (const float*)d_in[21];
  const float* Wcomb   = (const float*)d_in[22];
  const float* Wvocab  = (const float*)d_in[23];

  char* ws = (char*)d_ws;
  size_t off = 0;
  auto alloc = [&](size_t bytes)->char*{
    char* p = ws + off;
    off = (off + bytes + 255) & ~(size_t)255;
    return p;
  };

  // --- zero region (contiguous, re-zeroed every launch) ---
  u16* hF0      = (u16*)alloc((size_t)65536*2);
  u16* hB0      = (u16*)alloc((size_t)65536*2);
  float* cF     = (float*)alloc((size_t)65536*4);
  float* cB     = (float*)alloc((size_t)65536*4);
  u16* obf_zero = (u16*)alloc((size_t)65536*2);
  int* bar      = (int*)alloc(8192);   // 2048 ints; all barrier words in-bounds
  size_t zero_floats = ((size_t)131072*3 + (size_t)262144*2 + 8192)/4;
  int* flagsE = bar;          // 256 ints
  int* flagsD = bar + 256;    // 256 ints
  int* relE   = bar + 1024;   // own cache line, in-bounds
  int* relD   = bar + 1040;   // own cache line, in-bounds

  // --- non-zeroed state ---
  u16* hF1      = (u16*)alloc((size_t)65536*2);
  u16* hB1      = (u16*)alloc((size_t)65536*2);

  // --- weights (bf16) ---
  u16* Wconv_bf = (u16*)alloc((size_t)512*1024*2);
  u16* Wih_f_bf = (u16*)alloc((size_t)4096*512*2);
  u16* Wih_b_bf = (u16*)alloc((size_t)4096*512*2);
  u16* Wy_bf    = (u16*)alloc((size_t)4096*512*2);
  u16* Wh_bf    = (u16*)alloc((size_t)1024*2048*2);
  u16* Wc_bf    = (u16*)alloc((size_t)1024*2048*2);
  u16* Watt_bf  = (u16*)alloc((size_t)1024*2048*2);
  u16* Wca_bf   = (u16*)alloc((size_t)1024*2048*2);
  u16* Whp_bf   = (u16*)alloc((size_t)1024*1024*2);
  u16* Wv_bf    = (u16*)alloc((size_t)32000*1024*2);
  float* benc_f = (float*)alloc(4096*4);
  float* benc_b = (float*)alloc(4096*4);
  float* bdec   = (float*)alloc(4096*4);

  // --- activations ---
  u16* Aconv    = (u16*)alloc((size_t)3072*1024*2);
  u16* Xc       = (u16*)alloc((size_t)3072*512*2);
  u16* Gf       = (u16*)alloc((size_t)3072*4096*2);
  u16* Gb       = (u16*)alloc((size_t)3072*4096*2);
  u16* Ybf      = (u16*)alloc((size_t)3008*512*2);
  u16* Gy       = (u16*)alloc((size_t)3008*4096*2);
  u16* Aatt     = (u16*)alloc((size_t)3072*2048*2);
  u16* encP     = (u16*)alloc((size_t)3072*1024*2);
  u16* encWc    = (u16*)alloc((size_t)3072*1024*2);
  u16* cfbf     = (u16*)alloc((size_t)65536*2);
  u16* cbbf     = (u16*)alloc((size_t)65536*2);
  float* hdec0  = (float*)alloc((size_t)65536*4);
  u16* hbf0     = (u16*)alloc((size_t)65536*2);
  u16* hbf1     = (u16*)alloc((size_t)65536*2);
  float* cdec   = (float*)alloc((size_t)65536*4);
  float* hpart  = (float*)alloc((size_t)65536*4);
  float* sc     = (float*)alloc((size_t)64*2*48*4);
  float* combined=(float*)alloc((size_t)3008*1024*4);
  u16* Cbf      = (u16*)alloc((size_t)3008*1024*2);
  float2* partials=(float2*)alloc((size_t)3008*VNS*8);
  float* lse    = (float*)alloc(3008*4);
  float* gold   = (float*)alloc(3008*4);

  k_zero<<<256, 256, 0, stream>>>((float*)hF0, (long)zero_floats);

  auto cgrid = [](long n)->int{ long g = (n/4 + 255)/256; return (int)(g > 1024 ? 1024 : g); };
  k_cast_bf16<<<cgrid(4096*512), 256, 0, stream>>>(eWih_f, Wih_f_bf, (long)4096*512);
  k_cast_bf16<<<cgrid(4096*512), 256, 0, stream>>>(eWih_b, Wih_b_bf, (long)4096*512);
  k_cast_bf16<<<cgrid(1024*2048), 256, 0, stream>>>(Wh, Wh_bf, (long)1024*2048);
  k_cast_bf16<<<cgrid(1024*2048), 256, 0, stream>>>(Wc, Wc_bf, (long)1024*2048);
  k_cast_bf16<<<cgrid(1024*2048), 256, 0, stream>>>(Watt, Watt_bf, (long)1024*2048);
  k_cast_bf16<<<cgrid((long)32000*1024), 256, 0, stream>>>(Wvocab, Wv_bf, (long)32000*1024);

  k_addv<<<16, 256, 0, stream>>>(ebih_f, ebhh_f, benc_f, 4096);
  k_addv<<<16, 256, 0, stream>>>(ebih_b, ebhh_b, benc_b, 4096);
  k_addv<<<16, 256, 0, stream>>>(dbih, dbhh, bdec, 4096);

  k_repack_conv<<<1024, 256, 0, stream>>>(cnn_w, Wconv_bf);
  k_build_wy<<<8192, 256, 0, stream>>>(dWih, Wy_bf);
  k_split_wcomb<<<1024, 256, 0, stream>>>(Wcomb, Wca_bf, Whp_bf);

  k_gather_src<<<dim3(49, 64), 128, 0, stream>>>(src_ids, src_emb, Aconv);
  k_gather_y<<<dim3(47, 64), 128, 0, stream>>>(tgt_ids, tgt_emb, Ybf);

  // conv + input-gate precomputes
  k_gemm<true><<<dim3(48, 8), 256, 0, stream>>>(
      Aconv, 1024, Aconv, 1024, 1024, Wconv_bf, 1024, Xc, 512, cnn_b);
  k_gemm<true><<<dim3(48, 64), 256, 0, stream>>>(
      Xc, 512, Xc, 512, 512, Wih_f_bf, 512, Gf, 4096, benc_f);
  k_gemm<true><<<dim3(48, 64), 256, 0, stream>>>(
      Xc, 512, Xc, 512, 512, Wih_b_bf, 512, Gb, 4096, benc_b);
  k_gemm<true><<<dim3(47, 64), 256, 0, stream>>>(
      Ybf, 512, Ybf, 512, 512, Wy_bf, 512, Gy, 4096, bdec);

  // persistent bidirectional encoder (LDS-resident Whh slices)
  k_enc_persist<<<256, 256, 65536, stream>>>(
      eWhh_f, eWhh_b, Gf, Gb, hF0, hF1, hB0, hB1, cF, cB,
      Aatt, cfbf, cbbf, flagsE, relE);

  // decoder init
  k_gemm<false><<<dim3(1, 16), 256, 0, stream>>>(
      hF0, 1024, hB0, 1024, 1024, Wh_bf, 2048, hdec0, 1024, nullptr);
  k_cast_bf16<<<64, 256, 0, stream>>>(hdec0, hbf0, (long)65536);
  k_gemm<false><<<dim3(1, 16), 256, 0, stream>>>(
      cfbf, 1024, cbbf, 1024, 1024, Wc_bf, 2048, cdec, 1024, nullptr);
  // encP = enc_hiddens @ Watt^T, encWc = enc_hiddens @ Wcomb_a^T (both bf16)
  k_gemm<true><<<dim3(48, 16), 256, 0, stream>>>(
      Aatt, 2048, Aatt, 2048, 2048, Watt_bf, 2048, encP, 1024, nullptr);
  k_gemm<true><<<dim3(48, 16), 256, 0, stream>>>(
      Aatt, 2048, Aatt, 2048, 2048, Wca_bf, 2048, encWc, 1024, nullptr);

  // persistent decoder (LDS-resident Wdec / encP / encWc)
  k_dec_persist<<<256, 256, 131072, stream>>>(
      dWih, dWhh, Gy, encP, encWc, Whp_bf, hbf0, hbf1, cdec,
      hpart, sc, combined, Cbf, obf_zero, flagsD, relD);

  // vocab logsumexp + gold + final
  k_vocab_lse<<<dim3(47, VNS), 256, 0, stream>>>(Cbf, Wv_bf, partials);
  k_lse<<<12, 256, 0, stream>>>(partials, lse);
  k_gold<<<752, 256, 0, stream>>>(combined, Wvocab, tgt_ids, gold);
  k_final<<<1, 64, 0, stream>>>(gold, lse, tgt_ids, (float*)d_out);
}

// Round 5
// 3375.988 us; speedup vs baseline: 2.6766x; 2.6766x over previous
//
#include <hip/hip_runtime.h>
#include <hip/hip_bf16.h>
#include <math.h>

using f32x4 = __attribute__((ext_vector_type(4))) float;
using s16x8 = __attribute__((ext_vector_type(8))) short;
typedef unsigned short u16;
typedef unsigned int u32;
typedef unsigned long long u64;

#define MFMA16(a,b,c) __builtin_amdgcn_mfma_f32_16x16x32_bf16(a,b,c,0,0,0)
#define SCOPE_A __HIP_MEMORY_SCOPE_AGENT
#define FP 16   // flag padding (ints) = 64B

__device__ __forceinline__ float bf2f(u16 u){
  union { u32 i; float f; } v; v.i = ((u32)u) << 16; return v.f;
}
__device__ __forceinline__ u16 f2bf(float f){
  union { float f; u32 i; } v; v.f = f;
  u32 x = v.i;
  return (u16)((x + 0x7fffu + ((x >> 16) & 1u)) >> 16);
}
__device__ __forceinline__ float sigm(float x){ return 1.0f/(1.0f + expf(-x)); }

__device__ __forceinline__ s16x8 pack8(const float* p){
  s16x8 r;
  #pragma unroll
  for (int i = 0; i < 8; ++i) r[i] = (short)f2bf(p[i]);
  return r;
}

// device-coherent (L2-bypassing) accessors for cross-block data
__device__ __forceinline__ s16x8 coh_ld16B(const u16* p){
  union { u64 q[2]; s16x8 v; } u;
  u.q[0] = __hip_atomic_load((const u64*)p,       __ATOMIC_RELAXED, SCOPE_A);
  u.q[1] = __hip_atomic_load((const u64*)(p + 4), __ATOMIC_RELAXED, SCOPE_A);
  return u.v;
}
__device__ __forceinline__ u32 coh_ld32(const void* p){
  return __hip_atomic_load((const u32*)p, __ATOMIC_RELAXED, SCOPE_A);
}
__device__ __forceinline__ void coh_st32(void* p, u32 v){
  __hip_atomic_store((u32*)p, v, __ATOMIC_RELAXED, SCOPE_A);
}
__device__ __forceinline__ float u2f(u32 u){ union { u32 i; float f; } v; v.i = u; return v.f; }
__device__ __forceinline__ u32 f2u(float f){ union { float f; u32 i; } v; v.f = f; return v.i; }

// fence-free grid barrier: __syncthreads drains vmcnt per-wave (compiler emits
// s_waitcnt before s_barrier), so coherent data stores are complete before the
// arrival flag. 8-way fan-out release words limit same-line spin contention.
__device__ __forceinline__ void gbarf(int* flags, int* rel, int nb, int gen){
  __syncthreads();
  if (threadIdx.x == 0)
    __hip_atomic_store(flags + blockIdx.x*FP, gen, __ATOMIC_RELAXED, SCOPE_A);
  if (blockIdx.x == 0){
    for (int i = threadIdx.x; i < nb; i += blockDim.x)
      while (__hip_atomic_load(flags + i*FP, __ATOMIC_RELAXED, SCOPE_A) < gen)
        __builtin_amdgcn_s_sleep(1);
    __syncthreads();
    if (threadIdx.x < 8)
      __hip_atomic_store(rel + threadIdx.x*FP, gen, __ATOMIC_RELAXED, SCOPE_A);
  } else if (threadIdx.x == 0){
    const int* myrel = rel + (blockIdx.x >> 5)*FP;
    while (__hip_atomic_load(myrel, __ATOMIC_RELAXED, SCOPE_A) < gen)
      __builtin_amdgcn_s_sleep(1);
  }
  __syncthreads();
}

// ---------------- small utility kernels ----------------
__global__ void k_zero(float* __restrict__ p, long n){
  long i = (long)blockIdx.x*blockDim.x + threadIdx.x;
  long st = (long)gridDim.x*blockDim.x;
  for (; i < n; i += st) p[i] = 0.0f;
}

__global__ void k_cast_bf16(const float* __restrict__ src, u16* __restrict__ dst, long n){
  long i = ((long)blockIdx.x*blockDim.x + threadIdx.x)*4;
  long st = (long)gridDim.x*blockDim.x*4;
  for (; i < n; i += st){
    float4 v = *(const float4*)(src + i);
    *(ushort4*)(dst + i) = make_ushort4(f2bf(v.x), f2bf(v.y), f2bf(v.z), f2bf(v.w));
  }
}

__global__ void k_addv(const float* __restrict__ a, const float* __restrict__ b,
                       float* __restrict__ d, int n){
  int i = blockIdx.x*blockDim.x + threadIdx.x;
  if (i < n) d[i] = a[i] + b[i];
}

// cnn_w (512,512,2) -> Wconv_bf [512][1024] = [W0 | W1]
__global__ void k_repack_conv(const float* __restrict__ w, u16* __restrict__ dst){
  int i = blockIdx.x*256 + threadIdx.x;
  int o = i >> 9, ii = i & 511;
  dst[(size_t)o*1024 + ii]       = f2bf(w[((size_t)o*512 + ii)*2 + 0]);
  dst[(size_t)o*1024 + 512 + ii] = f2bf(w[((size_t)o*512 + ii)*2 + 1]);
}

// Wy[4096][512] = dec_Wih[:, 1024:1536]
__global__ void k_build_wy(const float* __restrict__ dWih, u16* __restrict__ Wy){
  int i = blockIdx.x*256 + threadIdx.x;
  int r = i >> 9, c = i & 511;
  Wy[(size_t)r*512 + c] = f2bf(dWih[(size_t)r*1536 + 1024 + c]);
}

// Wcomb (1024,3072) -> Wca [1024][2048], Whp [1024][1024]
__global__ void k_split_wcomb(const float* __restrict__ Wcomb,
                              u16* __restrict__ Wca, u16* __restrict__ Whp){
  int r = blockIdx.x;
  for (int c = threadIdx.x; c < 2048; c += 256)
    Wca[(size_t)r*2048 + c] = f2bf(Wcomb[(size_t)r*3072 + c]);
  for (int c = threadIdx.x; c < 1024; c += 256)
    Whp[(size_t)r*1024 + c] = f2bf(Wcomb[(size_t)r*3072 + 2048 + c]);
}

__global__ void k_gather_src(const int* __restrict__ ids, const float* __restrict__ emb,
                             u16* __restrict__ Aconv){
  int s = blockIdx.x;
  int b = blockIdx.y;
  int e = threadIdx.x*4;
  float4 v = make_float4(0.f,0.f,0.f,0.f);
  if (s < 48){ int id = ids[s*64 + b]; v = *(const float4*)(emb + (size_t)id*512 + e); }
  ushort4 u = make_ushort4(f2bf(v.x), f2bf(v.y), f2bf(v.z), f2bf(v.w));
  if (s < 48) *(ushort4*)(Aconv + ((size_t)(s*64 + b))*1024 + e) = u;
  if (s >= 1) *(ushort4*)(Aconv + ((size_t)((s-1)*64 + b))*1024 + 512 + e) = u;
}

__global__ void k_gather_y(const int* __restrict__ ids, const float* __restrict__ emb,
                           u16* __restrict__ Y){
  int t = blockIdx.x; int b = blockIdx.y; int e = threadIdx.x*4;
  int id = ids[t*64 + b];
  float4 v = *(const float4*)(emb + (size_t)id*512 + e);
  *(ushort4*)(Y + ((size_t)(t*64 + b))*512 + e) = make_ushort4(f2bf(v.x), f2bf(v.y), f2bf(v.z), f2bf(v.w));
}

// ---------------- universal MFMA GEMM (prologue use) ----------------
template<bool OUT_BF16>
__global__ __launch_bounds__(256) void k_gemm(
    const u16* __restrict__ A0, long lda0,
    const u16* __restrict__ A1, long lda1, int ksplit,
    const u16* __restrict__ W, int K,
    void* __restrict__ Out, long ldc,
    const float* __restrict__ bias)
{
  __shared__ __align__(16) u16 As[64][72];
  __shared__ __align__(16) u16 Ws[64][72];
  const int t = threadIdx.x;
  const int m0 = blockIdx.x*64, n0 = blockIdx.y*64;
  const int w = t >> 6, l = t & 63, lr = l & 15, lh = l >> 4;
  const int sr = t >> 2, sk = (t & 3) << 4;

  f32x4 acc[4] = {{0,0,0,0},{0,0,0,0},{0,0,0,0},{0,0,0,0}};

  for (int kc = 0; kc < K; kc += 64){
    {
      const u16* wp = W + (size_t)(n0 + sr)*K + kc + sk;
      *(s16x8*)&Ws[sr][sk]     = *(const s16x8*)wp;
      *(s16x8*)&Ws[sr][sk + 8] = *(const s16x8*)(wp + 8);
    }
    {
      const u16* ap = (kc < ksplit)
        ? A0 + (size_t)(m0 + sr)*lda0 + kc
        : A1 + (size_t)(m0 + sr)*lda1 + (kc - ksplit);
      ap += sk;
      *(s16x8*)&As[sr][sk]     = *(const s16x8*)ap;
      *(s16x8*)&As[sr][sk + 8] = *(const s16x8*)(ap + 8);
    }
    __syncthreads();
    #pragma unroll
    for (int kk = 0; kk < 64; kk += 32){
      s16x8 a = *(const s16x8*)&As[w*16 + lr][kk + lh*8];
      #pragma unroll
      for (int ct = 0; ct < 4; ++ct){
        s16x8 bfr = *(const s16x8*)&Ws[ct*16 + lr][kk + lh*8];
        acc[ct] = MFMA16(a, bfr, acc[ct]);
      }
    }
    __syncthreads();
  }
  #pragma unroll
  for (int ct = 0; ct < 4; ++ct){
    #pragma unroll
    for (int rr = 0; rr < 4; ++rr){
      long row = m0 + w*16 + lh*4 + rr;
      long col = n0 + ct*16 + lr;
      float v = acc[ct][rr];
      if (bias) v += bias[col];
      long oi = row*ldc + col;
      if (OUT_BF16) ((u16*)Out)[oi] = f2bf(v);
      else          ((float*)Out)[oi] = v;
    }
  }
}

// ---------------- persistent encoder ----------------
__global__ __launch_bounds__(256) void k_enc_persist(
    const float* __restrict__ WhhF, const float* __restrict__ WhhB,
    const u16* __restrict__ Gf, const u16* __restrict__ Gb,
    u16* __restrict__ hF0, u16* __restrict__ hF1,
    u16* __restrict__ hB0, u16* __restrict__ hB1,
    float* __restrict__ cF, float* __restrict__ cB,
    u16* __restrict__ Aatt, u16* __restrict__ cfbf, u16* __restrict__ cbbf,
    int* flags, int* rel)
{
  extern __shared__ char smem[];   // W slice [32][1024] bf16 swizzled, ROWB=2048
  const int t = threadIdx.x, blk = blockIdx.x;
  const int dir = blk >> 7;
  const int j0 = (blk & 127) << 3;
  const float* Wsrc = dir ? WhhB : WhhF;
  const u16* G = dir ? Gb : Gf;
  float* c = dir ? cB : cF;
  u16* cobf = dir ? cbbf : cfbf;
  u16* h0 = dir ? hB0 : hF0;
  u16* h1 = dir ? hB1 : hF1;

  for (int q = t; q < 32*128; q += 256){
    int row = q >> 7;
    int ck = (q & 127) << 3;
    int wrow = ((row >> 3)*1024) + j0 + (row & 7);
    s16x8 pk = pack8(Wsrc + (size_t)wrow*1024 + ck);
    *(s16x8*)(smem + row*2048 + ((ck*2) ^ ((row & 7) << 4))) = pk;
  }
  __syncthreads();

  const int w = t >> 6, l = t & 63, lr = l & 15, lh = l >> 4;
  const int lane_m = w*16 + lr;
  const int koff = lh*8;
  const char* wp0 = smem + lr*2048;
  const char* wp1 = smem + (16 + lr)*2048;
  const int xo = (lr & 7) << 4;
  const int jj = lr & 7, gsel = lr >> 3;
  const int j = j0 + jj;
  int gen = 0;

  for (int s = 0; s < 48; ++s){
    const u16* hin = (s & 1) ? h1 : h0;
    u16* hout      = (s & 1) ? h0 : h1;
    const int time = dir ? 47 - s : s;
    f32x4 a0 = {0,0,0,0}, a1 = {0,0,0,0};
    const u16* ap = hin + (size_t)lane_m*1024 + koff;
    #pragma unroll 8
    for (int kc = 0; kc < 1024; kc += 32){
      s16x8 av = coh_ld16B(ap + kc);
      int cb = (kc + koff)*2;
      s16x8 b0 = *(const s16x8*)(wp0 + (cb ^ xo));
      s16x8 b1 = *(const s16x8*)(wp1 + (cb ^ xo));
      a0 = MFMA16(av, b0, a0);
      a1 = MFMA16(av, b1, a1);
    }
    #pragma unroll
    for (int rr = 0; rr < 4; ++rr){
      float v0 = a0[rr], v1 = a1[rr];
      float p0 = __shfl_xor(v0, 8, 64);
      float p1 = __shfl_xor(v1, 8, 64);
      if (gsel == 0){
        int b = w*16 + lh*4 + rr;
        size_t grow = ((size_t)time*64 + b)*4096;
        float gi = v0 + bf2f(G[grow + j]);
        float gf = p0 + bf2f(G[grow + 1024 + j]);
        float gg = v1 + bf2f(G[grow + 2048 + j]);
        float go = p1 + bf2f(G[grow + 3072 + j]);
        float cn = sigm(gf)*c[b*1024 + j] + sigm(gi)*tanhf(gg);
        float hn = sigm(go)*tanhf(cn);
        c[b*1024 + j] = cn;
        u16 hb = f2bf(hn);
        u32 hi = __shfl_down((u32)hb, 1);
        if ((jj & 1) == 0)
          coh_st32((u32*)hout + ((b*1024 + j) >> 1), (u32)hb | (hi << 16));
        Aatt[((size_t)b*48 + time)*2048 + dir*1024 + j] = hb;
        if (s == 47) cobf[b*1024 + j] = f2bf(cn);
      }
    }
    if (s < 47) gbarf(flags, rel, 256, ++gen);
  }
}

// ---------------- persistent decoder ----------------
__global__ __launch_bounds__(256) void k_dec_persist(
    const float* __restrict__ dWih, const float* __restrict__ dWhh,
    const u16* __restrict__ Gy,
    const u16* __restrict__ encP, const u16* __restrict__ encWc,
    const u16* __restrict__ Whp,
    u16* __restrict__ hbf0, u16* __restrict__ hbf1,
    float* __restrict__ cdec,
    float* __restrict__ hpart, float* __restrict__ sc,
    u16* __restrict__ Cbf,
    const u16* __restrict__ obf_zero,
    int* flags, int* rel)
{
  extern __shared__ char smem[];
  const int t = threadIdx.x, blk = blockIdx.x;
  const int w = t >> 6, l = t & 63, lr = l & 15, lh = l >> 4;
  const int lane_m = w*16 + lr;
  const int koff = lh*8;

  u16* ePl = (u16*)smem;                  // [48][512]
  u16* eWl = (u16*)(smem + 49152);        // [48][512]
  float* hs = (float*)(smem + 98304);     // [512]
  float* es = (float*)(smem + 100352);    // [48]
  float* ea = es + 48;                    // [48]

  const int aidx = blk - 128;
  const int ab = aidx >> 1, kh = aidx & 1;

  if (blk < 128){
    const int j0s = blk << 3;
    for (int q = t; q < 32*256; q += 256){
      int row = q >> 8;
      int ck = (q & 255) << 3;
      int wrow = ((row >> 3)*1024) + j0s + (row & 7);
      const float* src = (ck < 1024) ? dWih + (size_t)wrow*1536 + ck
                                     : dWhh + (size_t)wrow*1024 + (ck - 1024);
      s16x8 pk = pack8(src);
      *(s16x8*)(smem + row*4096 + ((ck*2) ^ ((row & 7) << 4))) = pk;
    }
  } else {
    for (int q = t; q < 48*64; q += 256){
      int s = q >> 6;
      int ck = (q & 63) << 3;
      *(s16x8*)(ePl + s*512 + ck) =
        *(const s16x8*)(encP + ((size_t)ab*48 + s)*1024 + kh*512 + ck);
      *(s16x8*)(eWl + s*512 + ck) =
        *(const s16x8*)(encWc + ((size_t)ab*48 + s)*1024 + kh*512 + ck);
    }
  }
  __syncthreads();

  const int j0 = (blk & 127) << 3;
  const int jj = lr & 7, gsel = lr >> 3;
  const int j = j0 + jj;
  const char* wp0 = smem + lr*4096;
  const char* wp1 = smem + (16 + lr)*4096;
  const int xo = (lr & 7) << 4;

  int gen = 0;
  int cur = 0;

  for (int tt = 0; tt < 47; ++tt){
    const u16* hin  = cur ? hbf1 : hbf0;
    u16* hnew       = cur ? hbf0 : hbf1;

    if (blk < 128){
      // ---- ph1: gates = [o_prev | h] @ Wdec_slice^T + Gy -> LSTM
      const u16* Ao = tt ? (Cbf + (size_t)(tt - 1)*65536) : obf_zero;
      f32x4 a0 = {0,0,0,0}, a1 = {0,0,0,0};
      {
        const u16* ap = Ao + (size_t)lane_m*1024 + koff;
        #pragma unroll 8
        for (int kc = 0; kc < 1024; kc += 32){
          s16x8 av = coh_ld16B(ap + kc);
          int cb = (kc + koff)*2;
          s16x8 b0 = *(const s16x8*)(wp0 + (cb ^ xo));
          s16x8 b1 = *(const s16x8*)(wp1 + (cb ^ xo));
          a0 = MFMA16(av, b0, a0);
          a1 = MFMA16(av, b1, a1);
        }
      }
      {
        const u16* ap = hin + (size_t)lane_m*1024 + koff;
        #pragma unroll 8
        for (int kc = 0; kc < 1024; kc += 32){
          s16x8 av = coh_ld16B(ap + kc);
          int cb = (kc + 1024 + koff)*2;
          s16x8 b0 = *(const s16x8*)(wp0 + (cb ^ xo));
          s16x8 b1 = *(const s16x8*)(wp1 + (cb ^ xo));
          a0 = MFMA16(av, b0, a0);
          a1 = MFMA16(av, b1, a1);
        }
      }
      #pragma unroll
      for (int rr = 0; rr < 4; ++rr){
        float v0 = a0[rr], v1 = a1[rr];
        float p0 = __shfl_xor(v0, 8, 64);
        float p1 = __shfl_xor(v1, 8, 64);
        if (gsel == 0){
          int b = w*16 + lh*4 + rr;
          size_t grow = ((size_t)tt*64 + b)*4096;
          float gi = v0 + bf2f(Gy[grow + j]);
          float gf = p0 + bf2f(Gy[grow + 1024 + j]);
          float gg = v1 + bf2f(Gy[grow + 2048 + j]);
          float go = p1 + bf2f(Gy[grow + 3072 + j]);
          float cn = sigm(gf)*cdec[b*1024 + j] + sigm(gi)*tanhf(gg);
          float hn = sigm(go)*tanhf(cn);
          cdec[b*1024 + j] = cn;
          u16 hb = f2bf(hn);
          u32 hi = __shfl_down((u32)hb, 1);
          if ((jj & 1) == 0)
            coh_st32((u32*)hnew + ((b*1024 + j) >> 1), (u32)hb | (hi << 16));
        }
      }
    }
    gbarf(flags, rel, 256, ++gen);

    if (blk >= 128){
      // ---- ph2 (AW): partial scores over kh half
      const u32* h32 = (const u32*)hnew + (size_t)ab*512 + kh*256;
      for (int i = t; i < 256; i += 256){
        u32 v = coh_ld32(h32 + i);
        hs[2*i]     = bf2f((u16)(v & 0xffff));
        hs[2*i + 1] = bf2f((u16)(v >> 16));
      }
      __syncthreads();
      for (int s = w; s < 48; s += 4){
        float p = 0.f;
        #pragma unroll
        for (int i = 0; i < 8; ++i)
          p += hs[l + 64*i]*bf2f(ePl[s*512 + l + 64*i]);
        #pragma unroll
        for (int d = 32; d >= 1; d >>= 1) p += __shfl_xor(p, d, 64);
        if (l == 0) coh_st32(&sc[(ab*2 + kh)*48 + s], f2u(p));
      }
    } else if (blk < 64){
      // ---- ph2 (G 0..63): hpart = hnew @ Whp^T, 16 cols each
      const int n0 = blk << 4;
      const u16* ap = hnew + (size_t)lane_m*1024 + koff;
      const u16* wb = Whp + (size_t)(n0 + lr)*1024 + koff;
      f32x4 acc = {0,0,0,0};
      #pragma unroll 8
      for (int kc = 0; kc < 1024; kc += 32){
        s16x8 av = coh_ld16B(ap + kc);
        s16x8 bv = *(const s16x8*)(wb + kc);
        acc = MFMA16(av, bv, acc);
      }
      #pragma unroll
      for (int rr = 0; rr < 4; ++rr)
        coh_st32(&hpart[(size_t)(w*16 + lh*4 + rr)*1024 + n0 + lr], f2u(acc[rr]));
    }
    gbarf(flags, rel, 256, ++gen);

    if (blk >= 128){
      // ---- ph3 (AW): softmax + weighted encWc sum + combine
      if (t < 48) es[t] = u2f(coh_ld32(&sc[ab*96 + t])) + u2f(coh_ld32(&sc[ab*96 + 48 + t]));
      __syncthreads();
      float m = -INFINITY;
      for (int s = 0; s < 48; ++s) m = fmaxf(m, es[s]);
      if (t < 48) ea[t] = expf(es[t] - m);
      __syncthreads();
      float ssum = 0.f;
      for (int s = 0; s < 48; ++s) ssum += ea[s];
      float inv = 1.0f/ssum;
      int c0 = t*2;
      float acc0 = 0.f, acc1 = 0.f;
      for (int s = 0; s < 48; ++s){
        float wgt = ea[s];
        acc0 += wgt*bf2f(eWl[s*512 + c0]);
        acc1 += wgt*bf2f(eWl[s*512 + c0 + 1]);
      }
      int n = kh*512 + c0;
      float v0 = tanhf(u2f(coh_ld32(&hpart[(size_t)ab*1024 + n]))     + acc0*inv);
      float v1 = tanhf(u2f(coh_ld32(&hpart[(size_t)ab*1024 + n + 1])) + acc1*inv);
      size_t oi = (size_t)tt*65536 + (size_t)ab*1024 + n;
      coh_st32((u32*)Cbf + (oi >> 1), (u32)f2bf(v0) | ((u32)f2bf(v1) << 16));
      __syncthreads();
    }
    if (tt < 46) gbarf(flags, rel, 256, ++gen);
    cur ^= 1;
  }
}

// ---------------- fused vocab GEMM + online logsumexp ----------------
#define VNS 25
__global__ __launch_bounds__(256) void k_vocab_lse(
    const u16* __restrict__ Cbf, const u16* __restrict__ Wv, float2* __restrict__ partials)
{
  __shared__ __align__(16) u16 As[64][136];
  __shared__ __align__(16) u16 Ws[64][136];
  int rb = blockIdx.x, sp = blockIdx.y;
  int m0 = rb*64;
  int t = threadIdx.x, w = t >> 6, l = t & 63, lr = l & 15, lh = l >> 4;
  int sr = t >> 2, sk = (t & 3) << 5;
  float mrun[4] = {-INFINITY, -INFINITY, -INFINITY, -INFINITY};
  float srun[4] = {0.f, 0.f, 0.f, 0.f};

  for (int nt = 0; nt < 20; ++nt){
    int n0 = sp*1280 + nt*64;
    f32x4 acc[4] = {{0,0,0,0},{0,0,0,0},{0,0,0,0},{0,0,0,0}};
    for (int kc = 0; kc < 1024; kc += 128){
      const u16* ap = Cbf + (size_t)(m0 + sr)*1024 + kc + sk;
      const u16* wp = Wv  + (size_t)(n0 + sr)*1024 + kc + sk;
      #pragma unroll
      for (int q = 0; q < 4; ++q){
        *(s16x8*)&As[sr][sk + q*8] = *(const s16x8*)(ap + q*8);
        *(s16x8*)&Ws[sr][sk + q*8] = *(const s16x8*)(wp + q*8);
      }
      __syncthreads();
      #pragma unroll
      for (int kk = 0; kk < 128; kk += 32){
        s16x8 a = *(const s16x8*)&As[w*16 + lr][kk + lh*8];
        #pragma unroll
        for (int ct = 0; ct < 4; ++ct){
          s16x8 bfr = *(const s16x8*)&Ws[ct*16 + lr][kk + lh*8];
          acc[ct] = MFMA16(a, bfr, acc[ct]);
        }
      }
      __syncthreads();
    }
    #pragma unroll
    for (int rr = 0; rr < 4; ++rr){
      float tm = fmaxf(fmaxf(acc[0][rr], acc[1][rr]), fmaxf(acc[2][rr], acc[3][rr]));
      for (int d = 1; d < 16; d <<= 1) tm = fmaxf(tm, __shfl_xor(tm, d, 64));
      float ts = expf(acc[0][rr] - tm) + expf(acc[1][rr] - tm)
               + expf(acc[2][rr] - tm) + expf(acc[3][rr] - tm);
      for (int d = 1; d < 16; d <<= 1) ts += __shfl_xor(ts, d, 64);
      if (tm > mrun[rr]){ srun[rr] = srun[rr]*expf(mrun[rr] - tm) + ts; mrun[rr] = tm; }
      else srun[rr] += ts*expf(tm - mrun[rr]);
    }
  }
  if (lr == 0){
    #pragma unroll
    for (int rr = 0; rr < 4; ++rr){
      long row = m0 + w*16 + lh*4 + rr;
      partials[row*VNS + sp] = make_float2(mrun[rr], srun[rr]);
    }
  }
}

__global__ void k_lse(const float2* __restrict__ partials, float* __restrict__ lse){
  int r = blockIdx.x*256 + threadIdx.x;
  if (r >= 3008) return;
  float m = -INFINITY, s = 0.f;
  for (int i = 0; i < VNS; ++i){
    float2 p = partials[r*VNS + i];
    if (p.x > m){ s = s*expf(m - p.x) + p.y; m = p.x; }
    else s += p.y*expf(p.x - m);
  }
  lse[r] = m + logf(s);
}

__global__ __launch_bounds__(256) void k_gold(const u16* __restrict__ Cbf,
                                              const u16* __restrict__ Wv,
                                              const int* __restrict__ tgt,
                                              float* __restrict__ gold){
  int w = threadIdx.x >> 6, l = threadIdx.x & 63;
  int r = blockIdx.x*4 + w;
  int tt = r >> 6, b = r & 63;
  int gid = tgt[(tt + 1)*64 + b];
  const u16* cp = Cbf + (size_t)r*1024;
  const u16* wp = Wv + (size_t)gid*1024;
  float p = 0.f;
  for (int i = l; i < 1024; i += 64) p += bf2f(cp[i])*bf2f(wp[i]);
  for (int d = 32; d >= 1; d >>= 1) p += __shfl_xor(p, d, 64);
  if (l == 0) gold[r] = p;
}

__global__ void k_final(const float* __restrict__ gold, const float* __restrict__ lse,
                        const int* __restrict__ tgt, float* __restrict__ out){
  int b = threadIdx.x;
  if (b >= 64) return;
  float acc = 0.f;
  for (int t = 0; t < 47; ++t){
    int gid = tgt[(t + 1)*64 + b];
    if (gid != 0) acc += gold[t*64 + b] - lse[t*64 + b];
  }
  out[b] = acc;
}

// ---------------- host ----------------
extern "C" void kernel_launch(void* const* d_in, const int* in_sizes, int n_in,
                              void* d_out, int out_size, void* d_ws, size_t ws_size,
                              hipStream_t stream)
{
  (void)in_sizes; (void)n_in; (void)out_size; (void)ws_size;
  const int*   src_ids = (const int*)d_in[0];
  const int*   tgt_ids = (const int*)d_in[1];
  const float* src_emb = (const float*)d_in[3];
  const float* tgt_emb = (const float*)d_in[4];
  const float* cnn_w   = (const float*)d_in[5];
  const float* cnn_b   = (const float*)d_in[6];
  const float* eWih_f  = (const float*)d_in[7];
  const float* eWhh_f  = (const float*)d_in[8];
  const float* ebih_f  = (const float*)d_in[9];
  const float* ebhh_f  = (const float*)d_in[10];
  const float* eWih_b  = (const float*)d_in[11];
  const float* eWhh_b  = (const float*)d_in[12];
  const float* ebih_b  = (const float*)d_in[13];
  const float* ebhh_b  = (const float*)d_in[14];
  const float* dWih    = (const float*)d_in[15];
  const float* dWhh    = (const float*)d_in[16];
  const float* dbih    = (const float*)d_in[17];
  const float* dbhh    = (const float*)d_in[18];
  const float* Wh      = (const float*)d_in[19];
  const float* Wc      = (const float*)d_in[20];
  const float* Watt    = (const float*)d_in[21];
  const float* Wcomb   = (const float*)d_in[22];
  const float* Wvocab  = (const float*)d_in[23];

  char* ws = (char*)d_ws;
  size_t off = 0;
  auto alloc = [&](size_t bytes)->char*{
    char* p = ws + off;
    off = (off + bytes + 255) & ~(size_t)255;
    return p;
  };

  // --- zero region (contiguous, re-zeroed every launch) ---
  u16* hF0      = (u16*)alloc((size_t)65536*2);   // 131072 B
  u16* hB0      = (u16*)alloc((size_t)65536*2);   // 131072 B
  float* cF     = (float*)alloc((size_t)65536*4); // 262144 B
  float* cB     = (float*)alloc((size_t)65536*4); // 262144 B
  u16* obf_zero = (u16*)alloc((size_t)65536*2);   // 131072 B
  int* bar      = (int*)alloc(65536);             // 16384 ints, padded flags
  size_t zero_floats = ((size_t)131072*3 + (size_t)262144*2 + 65536)/4;
  int* flagsE = bar;            // 256*FP ints
  int* relE   = bar + 4096;     // 8*FP ints
  int* flagsD = bar + 8192;     // 256*FP ints
  int* relD   = bar + 12288;    // 8*FP ints

  // --- non-zeroed state ---
  u16* hF1      = (u16*)alloc((size_t)65536*2);
  u16* hB1      = (u16*)alloc((size_t)65536*2);

  // --- weights (bf16) ---
  u16* Wconv_bf = (u16*)alloc((size_t)512*1024*2);
  u16* Wih_f_bf = (u16*)alloc((size_t)4096*512*2);
  u16* Wih_b_bf = (u16*)alloc((size_t)4096*512*2);
  u16* Wy_bf    = (u16*)alloc((size_t)4096*512*2);
  u16* Wh_bf    = (u16*)alloc((size_t)1024*2048*2);
  u16* Wc_bf    = (u16*)alloc((size_t)1024*2048*2);
  u16* Watt_bf  = (u16*)alloc((size_t)1024*2048*2);
  u16* Wca_bf   = (u16*)alloc((size_t)1024*2048*2);
  u16* Whp_bf   = (u16*)alloc((size_t)1024*1024*2);
  u16* Wv_bf    = (u16*)alloc((size_t)32000*1024*2);
  float* benc_f = (float*)alloc(4096*4);
  float* benc_b = (float*)alloc(4096*4);
  float* bdec   = (float*)alloc(4096*4);

  // --- activations ---
  u16* Aconv    = (u16*)alloc((size_t)3072*1024*2);
  u16* Xc       = (u16*)alloc((size_t)3072*512*2);
  u16* Gf       = (u16*)alloc((size_t)3072*4096*2);
  u16* Gb       = (u16*)alloc((size_t)3072*4096*2);
  u16* Ybf      = (u16*)alloc((size_t)3008*512*2);
  u16* Gy       = (u16*)alloc((size_t)3008*4096*2);
  u16* Aatt     = (u16*)alloc((size_t)3072*2048*2);
  u16* encP     = (u16*)alloc((size_t)3072*1024*2);
  u16* encWc    = (u16*)alloc((size_t)3072*1024*2);
  u16* cfbf     = (u16*)alloc((size_t)65536*2);
  u16* cbbf     = (u16*)alloc((size_t)65536*2);
  float* hdec0  = (float*)alloc((size_t)65536*4);
  u16* hbf0     = (u16*)alloc((size_t)65536*2);
  u16* hbf1     = (u16*)alloc((size_t)65536*2);
  float* cdec   = (float*)alloc((size_t)65536*4);
  float* hpart  = (float*)alloc((size_t)65536*4);
  float* sc     = (float*)alloc((size_t)64*2*48*4);
  u16* Cbf      = (u16*)alloc((size_t)3008*1024*2);
  float2* partials=(float2*)alloc((size_t)3008*VNS*8);
  float* lse    = (float*)alloc(3008*4);
  float* gold   = (float*)alloc(3008*4);

  k_zero<<<256, 256, 0, stream>>>((float*)hF0, (long)zero_floats);

  auto cgrid = [](long n)->int{ long g = (n/4 + 255)/256; return (int)(g > 1024 ? 1024 : g); };
  k_cast_bf16<<<cgrid(4096*512), 256, 0, stream>>>(eWih_f, Wih_f_bf, (long)4096*512);
  k_cast_bf16<<<cgrid(4096*512), 256, 0, stream>>>(eWih_b, Wih_b_bf, (long)4096*512);
  k_cast_bf16<<<cgrid(1024*2048), 256, 0, stream>>>(Wh, Wh_bf, (long)1024*2048);
  k_cast_bf16<<<cgrid(1024*2048), 256, 0, stream>>>(Wc, Wc_bf, (long)1024*2048);
  k_cast_bf16<<<cgrid(1024*2048), 256, 0, stream>>>(Watt, Watt_bf, (long)1024*2048);
  k_cast_bf16<<<cgrid((long)32000*1024), 256, 0, stream>>>(Wvocab, Wv_bf, (long)32000*1024);

  k_addv<<<16, 256, 0, stream>>>(ebih_f, ebhh_f, benc_f, 4096);
  k_addv<<<16, 256, 0, stream>>>(ebih_b, ebhh_b, benc_b, 4096);
  k_addv<<<16, 256, 0, stream>>>(dbih, dbhh, bdec, 4096);

  k_repack_conv<<<1024, 256, 0, stream>>>(cnn_w, Wconv_bf);
  k_build_wy<<<8192, 256, 0, stream>>>(dWih, Wy_bf);
  k_split_wcomb<<<1024, 256, 0, stream>>>(Wcomb, Wca_bf, Whp_bf);

  k_gather_src<<<dim3(49, 64), 128, 0, stream>>>(src_ids, src_emb, Aconv);
  k_gather_y<<<dim3(47, 64), 128, 0, stream>>>(tgt_ids, tgt_emb, Ybf);

  // conv + input-gate precomputes
  k_gemm<true><<<dim3(48, 8), 256, 0, stream>>>(
      Aconv, 1024, Aconv, 1024, 1024, Wconv_bf, 1024, Xc, 512, cnn_b);
  k_gemm<true><<<dim3(48, 64), 256, 0, stream>>>(
      Xc, 512, Xc, 512, 512, Wih_f_bf, 512, Gf, 4096, benc_f);
  k_gemm<true><<<dim3(48, 64), 256, 0, stream>>>(
      Xc, 512, Xc, 512, 512, Wih_b_bf, 512, Gb, 4096, benc_b);
  k_gemm<true><<<dim3(47, 64), 256, 0, stream>>>(
      Ybf, 512, Ybf, 512, 512, Wy_bf, 512, Gy, 4096, bdec);

  // persistent bidirectional encoder (LDS-resident Whh slices)
  k_enc_persist<<<256, 256, 65536, stream>>>(
      eWhh_f, eWhh_b, Gf, Gb, hF0, hF1, hB0, hB1, cF, cB,
      Aatt, cfbf, cbbf, flagsE, relE);

  // decoder init
  k_gemm<false><<<dim3(1, 16), 256, 0, stream>>>(
      hF0, 1024, hB0, 1024, 1024, Wh_bf, 2048, hdec0, 1024, nullptr);
  k_cast_bf16<<<64, 256, 0, stream>>>(hdec0, hbf0, (long)65536);
  k_gemm<false><<<dim3(1, 16), 256, 0, stream>>>(
      cfbf, 1024, cbbf, 1024, 1024, Wc_bf, 2048, cdec, 1024, nullptr);
  // encP = enc_hiddens @ Watt^T, encWc = enc_hiddens @ Wcomb_a^T (both bf16)
  k_gemm<true><<<dim3(48, 16), 256, 0, stream>>>(
      Aatt, 2048, Aatt, 2048, 2048, Watt_bf, 2048, encP, 1024, nullptr);
  k_gemm<true><<<dim3(48, 16), 256, 0, stream>>>(
      Aatt, 2048, Aatt, 2048, 2048, Wca_bf, 2048, encWc, 1024, nullptr);

  // persistent decoder (LDS-resident Wdec / encP / encWc, coherent-atomic data)
  k_dec_persist<<<256, 256, 131072, stream>>>(
      dWih, dWhh, Gy, encP, encWc, Whp_bf, hbf0, hbf1, cdec,
      hpart, sc, Cbf, obf_zero, flagsD, relD);

  // vocab logsumexp + gold + final
  k_vocab_lse<<<dim3(47, VNS), 256, 0, stream>>>(Cbf, Wv_bf, partials);
  k_lse<<<12, 256, 0, stream>>>(partials, lse);
  k_gold<<<752, 256, 0, stream>>>(Cbf, Wv_bf, tgt_ids, gold);
  k_final<<<1, 64, 0, stream>>>(gold, lse, tgt_ids, (float*)d_out);
}